// Round 8
// baseline (498.318 us; speedup 1.0000x reference)
//
#include <hip/hip_runtime.h>
#include <hip/hip_bf16.h>
#include <math.h>

#define T_LEN 4096
#define D_DIM 512
#define F_DIM 8192
#define NCHUNK 64
#define CLEN 64

typedef short short8 __attribute__((ext_vector_type(8)));
typedef float f32x4 __attribute__((ext_vector_type(4)));
typedef unsigned short u16;
typedef unsigned int u32;

// ---------------- helpers ----------------
__device__ inline float wave_sum(float v) {
#pragma unroll
  for (int o = 32; o; o >>= 1) v += __shfl_xor(v, o);
  return v;
}

__device__ inline u16 f2bf_bits(float v) {
  __hip_bfloat16 h = __float2bfloat16(v);
  return *(u16*)&h;
}

__device__ inline float bf2f(u16 u) {
  u32 x = ((u32)u) << 16;
  return *(float*)&x;
}

__device__ inline void gl_lds16(const void* g, void* l) {
  __builtin_amdgcn_global_load_lds((const __attribute__((address_space(1))) void*)g,
                                   (__attribute__((address_space(3))) void*)l, 16, 0, 0);
}

// start[] may arrive as 1-byte bools or int32 {0,1}.
__global__ void detect_start(const unsigned char* __restrict__ s8, int* __restrict__ mode) {
  __shared__ int found;
  if (threadIdx.x == 0) found = 0;
  __syncthreads();
  for (int i = threadIdx.x; i < 4096; i += 256)
    if ((i & 3) && s8[i]) found = 1;  // benign race, same value
  __syncthreads();
  if (threadIdx.x == 0) mode[0] = found;  // 1 = byte layout, 0 = int32 layout
}

__device__ inline int read_start(const unsigned char* s8, const int* s32, int mode, int t) {
  return mode ? (int)s8[t] : s32[t];
}

// ---------------- fp32 -> bf16(bits) convert (plain) ----------------
__global__ void f2bf(const float* __restrict__ s, u16* __restrict__ d, int n) {
  int i = blockIdx.x * 256 + threadIdx.x;
  if (i < n) d[i] = f2bf_bits(s[i]);
}

// fused per-layer weight conversion:
//   wcat = concat [Wtr_l; Wc_l] (128 x 512), unswizzled (BK=32 gemm)
//   w0bf: K-permute (f = r*128+2c+b <- b*4096+r*64+c) + granule swizzle by (d&7)
__global__ void k_conv(const float* __restrict__ wtr, const float* __restrict__ wc,
                       u16* __restrict__ wcat, const float* __restrict__ w0,
                       u16* __restrict__ w0bf) {
  int i = blockIdx.x * 256 + threadIdx.x;
  if (i < 128 * D_DIM) {
    float v = (i < 64 * D_DIM) ? wtr[i] : wc[i - 64 * D_DIM];
    wcat[i] = f2bf_bits(v);
  }
  int j = i - 128 * D_DIM;
  if (j >= 0 && j < D_DIM * F_DIM) {
    int d = j >> 13, f = j & 8191;
    int r = f >> 7, rem = f & 127;
    int c = rem >> 1, b = rem & 1;
    float v = w0[(size_t)d * 8192 + b * 4096 + r * 64 + c];
    w0bf[(size_t)d * 8192 + (f ^ ((d & 7) << 3))] = f2bf_bits(v);
  }
}

// ---------------- small MFMA GEMM (64x64 tile, BK=32, sync staging) — trct & W1 ----------------
template <int BM, int BN, int WR, int WC>
__global__ __launch_bounds__(256) void gemm_bt(const u16* __restrict__ A,
                                               const u16* __restrict__ B,
                                               float* __restrict__ C, int M, int N, int K) {
  constexpr int BK = 32;
  constexpr int MT = BM / (WR * 16);
  constexpr int NT = BN / (WC * 16);
  constexpr int AG = BM / 64;
  constexpr int BG = BN / 64;
  __shared__ u16 sA[BM * BK];
  __shared__ u16 sB[BN * BK];
  const int m0 = blockIdx.x * BM;
  const int n0 = blockIdx.y * BN;
  const int tid = threadIdx.x;
  const int wave = tid >> 6;
  const int lane = tid & 63;
  const int wr = wave / WC;
  const int wc = wave % WC;
  const int row_l = tid >> 2;
  const int c8 = (tid & 3) << 3;
  const int frow = lane & 15;
  const int fcol = (lane >> 4) << 3;

  f32x4 acc[MT][NT];
#pragma unroll
  for (int i = 0; i < MT; ++i)
#pragma unroll
    for (int j = 0; j < NT; ++j) acc[i][j] = (f32x4){0.f, 0.f, 0.f, 0.f};

  for (int k0 = 0; k0 < K; k0 += BK) {
#pragma unroll
    for (int j = 0; j < AG; ++j) {
      uint4 v = *(const uint4*)(A + (size_t)(m0 + j * 64 + row_l) * K + (k0 + c8));
      *(uint4*)(sA + (j * 64 + row_l) * BK + c8) = v;
    }
#pragma unroll
    for (int j = 0; j < BG; ++j) {
      uint4 v = *(const uint4*)(B + (size_t)(n0 + j * 64 + row_l) * K + (k0 + c8));
      *(uint4*)(sB + (j * 64 + row_l) * BK + c8) = v;
    }
    __syncthreads();
    short8 af[MT], bfr[NT];
#pragma unroll
    for (int i = 0; i < MT; ++i)
      af[i] = *(const short8*)(sA + (wr * MT * 16 + i * 16 + frow) * BK + fcol);
#pragma unroll
    for (int j = 0; j < NT; ++j)
      bfr[j] = *(const short8*)(sB + (wc * NT * 16 + j * 16 + frow) * BK + fcol);
#pragma unroll
    for (int i = 0; i < MT; ++i)
#pragma unroll
      for (int j = 0; j < NT; ++j)
        acc[i][j] = __builtin_amdgcn_mfma_f32_16x16x32_bf16(af[i], bfr[j], acc[i][j], 0, 0, 0);
    __syncthreads();
  }
#pragma unroll
  for (int i = 0; i < MT; ++i) {
    const int rbase = m0 + wr * MT * 16 + i * 16 + ((lane >> 4) << 2);
#pragma unroll
    for (int j = 0; j < NT; ++j) {
      const int col = n0 + wc * NT * 16 + j * 16 + (lane & 15);
#pragma unroll
      for (int rg = 0; rg < 4; ++rg) C[(size_t)(rbase + rg) * N + col] = acc[i][j][rg];
    }
  }
}

// ---------------- 128x128 MFMA GEMM, BK=64, XOR-swizzled operands, split-K, bf16 partials ----
// (retained for low-workspace fallback paths)
// A, B global layout: row-major with 16B granule g of each row stored at g ^ (row&7).
__global__ __launch_bounds__(256) void gemm128(const u16* __restrict__ A,
                                               const u16* __restrict__ B,
                                               u16* __restrict__ Cp, size_t pstride, int N,
                                               int Ktot) {
  __shared__ u16 sA[128 * 64];
  __shared__ u16 sB[128 * 64];
  const int tid = threadIdx.x;
  const int wave = tid >> 6;
  const int lane = tid & 63;
  const int wr = wave >> 1;
  const int wc = wave & 1;
  const int m0 = blockIdx.x * 128;
  const int n0 = blockIdx.y * 128;
  const int ks = blockIdx.z;
  const int Kper = Ktot / gridDim.z;
  const int kb = ks * Kper;
  const int row_s = tid >> 3;     // 0..31 staging row within 32-row group
  const int g8 = (tid & 7) << 3;  // granule offset (elems)
  const int frow = lane & 15;
  const int quad = lane >> 4;
  const int sw = frow & 7;

  f32x4 acc[4][4];
#pragma unroll
  for (int i = 0; i < 4; ++i)
#pragma unroll
    for (int j = 0; j < 4; ++j) acc[i][j] = (f32x4){0.f, 0.f, 0.f, 0.f};

  for (int k0 = kb; k0 < kb + Kper; k0 += 64) {
#pragma unroll
    for (int j = 0; j < 4; ++j) {
      gl_lds16(A + (size_t)(m0 + j * 32 + row_s) * Ktot + (k0 + g8), sA + j * 2048 + wave * 512);
      gl_lds16(B + (size_t)(n0 + j * 32 + row_s) * Ktot + (k0 + g8), sB + j * 2048 + wave * 512);
    }
    asm volatile("s_waitcnt vmcnt(0)" ::: "memory");
    __syncthreads();
#pragma unroll
    for (int kk = 0; kk < 2; ++kk) {
      const int gA = (((kk << 2) | quad) ^ sw) << 3;  // swizzled elem offset in row
      short8 af[4], bfr[4];
#pragma unroll
      for (int i = 0; i < 4; ++i)
        af[i] = *(const short8*)(sA + (wr * 64 + i * 16 + frow) * 64 + gA);
#pragma unroll
      for (int j = 0; j < 4; ++j)
        bfr[j] = *(const short8*)(sB + (wc * 64 + j * 16 + frow) * 64 + gA);
#pragma unroll
      for (int i = 0; i < 4; ++i)
#pragma unroll
        for (int j = 0; j < 4; ++j)
          acc[i][j] = __builtin_amdgcn_mfma_f32_16x16x32_bf16(af[i], bfr[j], acc[i][j], 0, 0, 0);
    }
    __syncthreads();
  }
#pragma unroll
  for (int i = 0; i < 4; ++i) {
    const int rbase = m0 + wr * 64 + i * 16 + ((lane >> 4) << 2);
#pragma unroll
    for (int j = 0; j < 4; ++j) {
      const int col = n0 + wc * 64 + j * 16 + (lane & 15);
#pragma unroll
      for (int rg = 0; rg < 4; ++rg)
        Cp[(size_t)ks * pstride + (size_t)(rbase + rg) * N + col] = f2bf_bits(acc[i][j][rg]);
    }
  }
}

// ---------------- 256x128 MFMA GEMM, merged 4-phase counted pipeline (fallback; 42us) ---------
// Proven v4 structure. See R4/R7 notes. KS=4 path.
__global__ __launch_bounds__(512, 2) void gemm_8ph(const u16* __restrict__ A,
                                                   const u16* __restrict__ B,
                                                   u16* __restrict__ Cp, size_t pstride, int N,
                                                   int Ktot) {
  extern __shared__ u16 smem[];
  u16* sA = smem;          // [2][256*64]
  u16* sB = smem + 32768;  // [2][128*64]
  const int tid = threadIdx.x;
  const int wave = tid >> 6;
  const int lane = tid & 63;
  const int wr = wave >> 1;  // 0..3 -> 64-row group
  const int wc = wave & 1;   // 0..1 -> 64-col group
  const int m0 = blockIdx.x * 256;
  const int n0 = blockIdx.y * 128;
  const int ks = blockIdx.z;
  const int Kper = Ktot / gridDim.z;
  const int kb = ks * Kper;
  const int NITER = Kper >> 7;  // 128 K per iteration (2 x BK=64 tiles)
  const int r_l = tid >> 3;     // row within 64-row load group
  const int g8 = (tid & 7) << 3;
  const int frow = lane & 15;
  const int quad = lane >> 4;
  const int sw = frow & 7;
  const int o0 = (quad ^ sw) << 3;        // swizzled elem offset, kk=0
  const int o1 = ((4 | quad) ^ sw) << 3;  // swizzled elem offset, kk=1

  const u16* Abase = A + (size_t)(m0 + r_l) * Ktot + g8;
  const u16* Bbase = B + (size_t)(n0 + r_l) * Ktot + g8;

#define STAGE_A(l, k0, b) \
  gl_lds16(Abase + (size_t)(l) * 64 * Ktot + (k0), sA + (b)*16384 + (l)*4096 + wave * 512)
#define STAGE_B(l, k0, b) \
  gl_lds16(Bbase + (size_t)(l) * 64 * Ktot + (k0), sB + (b)*8192 + (l)*4096 + wave * 512)
#define RD_A(dst, b, qm_)                                               \
  do {                                                                  \
    const u16* _p = sA + (b)*16384 + (wr * 64 + (qm_)*32 + frow) * 64;  \
    dst[0][0] = *(const short8*)(_p + o0);                              \
    dst[0][1] = *(const short8*)(_p + o1);                              \
    dst[1][0] = *(const short8*)(_p + 1024 + o0);                       \
    dst[1][1] = *(const short8*)(_p + 1024 + o1);                       \
  } while (0)
#define RD_B(dst, b, half_)                                              \
  do {                                                                   \
    const u16* _p = sB + (b)*8192 + (wc * 64 + (half_)*32 + frow) * 64;  \
    dst[0][0] = *(const short8*)(_p + o0);                               \
    dst[0][1] = *(const short8*)(_p + o1);                               \
    dst[1][0] = *(const short8*)(_p + 1024 + o0);                        \
    dst[1][1] = *(const short8*)(_p + 1024 + o1);                        \
  } while (0)
#define MFMA_QPAIR(ar, b0_, b1_, qm_)                                               \
  do {                                                                              \
    _Pragma("unroll") for (int f = 0; f < 2; ++f) _Pragma("unroll") for (int g = 0; \
                                                                         g < 2;    \
                                                                         ++g)      \
        _Pragma("unroll") for (int kk = 0; kk < 2; ++kk) acc[(qm_)*2 + f][g] =      \
            __builtin_amdgcn_mfma_f32_16x16x32_bf16(ar[f][kk], b0_[g][kk],          \
                                                    acc[(qm_)*2 + f][g], 0, 0, 0); \
    _Pragma("unroll") for (int f = 0; f < 2; ++f) _Pragma("unroll") for (int g = 0; \
                                                                         g < 2;    \
                                                                         ++g)      \
        _Pragma("unroll") for (int kk = 0; kk < 2; ++kk) acc[(qm_)*2 + f][2 + g] =  \
            __builtin_amdgcn_mfma_f32_16x16x32_bf16(ar[f][kk], b1_[g][kk],          \
                                                    acc[(qm_)*2 + f][2 + g], 0, 0,  \
                                                    0);                             \
  } while (0)

  f32x4 acc[4][4];
#pragma unroll
  for (int i = 0; i < 4; ++i)
#pragma unroll
    for (int j = 0; j < 4; ++j) acc[i][j] = (f32x4){0.f, 0.f, 0.f, 0.f};

  short8 af_lo[2][2];
  short8 af_hi[2][2];
  short8 bfr0[2][2];
  short8 bfr1[2][2];

  STAGE_A(0, kb, 0);
  STAGE_A(1, kb, 0);
  STAGE_A(2, kb, 0);
  STAGE_A(3, kb, 0);
  STAGE_B(0, kb, 0);
  STAGE_B(1, kb, 0);
  asm volatile("s_waitcnt vmcnt(0)" ::: "memory");
  __builtin_amdgcn_s_barrier();

  for (int I = 0; I < NITER; ++I) {
    const int k0e = kb + (I << 7);
    const bool nl = (I < NITER - 1);

    // ---- P0 ----
    RD_A(af_lo, 0, 0);
    RD_B(bfr0, 0, 0);
    RD_B(bfr1, 0, 1);
    STAGE_A(0, k0e + 64, 1);
    STAGE_A(1, k0e + 64, 1);
    STAGE_A(2, k0e + 64, 1);
    STAGE_A(3, k0e + 64, 1);
    STAGE_B(0, k0e + 64, 1);
    STAGE_B(1, k0e + 64, 1);
    __builtin_amdgcn_s_barrier();
    asm volatile("s_waitcnt lgkmcnt(0)" ::: "memory");
    __builtin_amdgcn_sched_barrier(0);
    __builtin_amdgcn_s_setprio(1);
    MFMA_QPAIR(af_lo, bfr0, bfr1, 0);
    __builtin_amdgcn_s_setprio(0);
    __builtin_amdgcn_s_barrier();

    // ---- P1 ----
    RD_A(af_hi, 0, 1);
    __builtin_amdgcn_s_barrier();
    asm volatile("s_waitcnt lgkmcnt(0)" ::: "memory");
    __builtin_amdgcn_sched_barrier(0);
    __builtin_amdgcn_s_setprio(1);
#pragma unroll
    for (int f = 0; f < 2; ++f)
#pragma unroll
      for (int g = 0; g < 2; ++g)
#pragma unroll
        for (int kk = 0; kk < 2; ++kk)
          acc[2 + f][2 + g] = __builtin_amdgcn_mfma_f32_16x16x32_bf16(
              af_hi[f][kk], bfr1[g][kk], acc[2 + f][2 + g], 0, 0, 0);
#pragma unroll
    for (int f = 0; f < 2; ++f)
#pragma unroll
      for (int g = 0; g < 2; ++g)
#pragma unroll
        for (int kk = 0; kk < 2; ++kk)
          acc[2 + f][g] = __builtin_amdgcn_mfma_f32_16x16x32_bf16(af_hi[f][kk], bfr0[g][kk],
                                                                  acc[2 + f][g], 0, 0, 0);
    __builtin_amdgcn_s_setprio(0);
    asm volatile("s_waitcnt vmcnt(0)" ::: "memory");
    __builtin_amdgcn_s_barrier();

    // ---- P2 ----
    RD_A(af_lo, 1, 0);
    RD_B(bfr0, 1, 0);
    RD_B(bfr1, 1, 1);
    if (nl) {
      STAGE_A(0, k0e + 128, 0);
      STAGE_A(1, k0e + 128, 0);
      STAGE_A(2, k0e + 128, 0);
      STAGE_A(3, k0e + 128, 0);
      STAGE_B(0, k0e + 128, 0);
      STAGE_B(1, k0e + 128, 0);
    }
    __builtin_amdgcn_s_barrier();
    asm volatile("s_waitcnt lgkmcnt(0)" ::: "memory");
    __builtin_amdgcn_sched_barrier(0);
    __builtin_amdgcn_s_setprio(1);
    MFMA_QPAIR(af_lo, bfr0, bfr1, 0);
    __builtin_amdgcn_s_setprio(0);
    __builtin_amdgcn_s_barrier();

    // ---- P3 ----
    RD_A(af_hi, 1, 1);
    __builtin_amdgcn_s_barrier();
    asm volatile("s_waitcnt lgkmcnt(0)" ::: "memory");
    __builtin_amdgcn_sched_barrier(0);
    __builtin_amdgcn_s_setprio(1);
#pragma unroll
    for (int f = 0; f < 2; ++f)
#pragma unroll
      for (int g = 0; g < 2; ++g)
#pragma unroll
        for (int kk = 0; kk < 2; ++kk)
          acc[2 + f][2 + g] = __builtin_amdgcn_mfma_f32_16x16x32_bf16(
              af_hi[f][kk], bfr1[g][kk], acc[2 + f][2 + g], 0, 0, 0);
#pragma unroll
    for (int f = 0; f < 2; ++f)
#pragma unroll
      for (int g = 0; g < 2; ++g)
#pragma unroll
        for (int kk = 0; kk < 2; ++kk)
          acc[2 + f][g] = __builtin_amdgcn_mfma_f32_16x16x32_bf16(af_hi[f][kk], bfr0[g][kk],
                                                                  acc[2 + f][g], 0, 0, 0);
    __builtin_amdgcn_s_setprio(0);
    if (nl) asm volatile("s_waitcnt vmcnt(0)" ::: "memory");
    __builtin_amdgcn_s_barrier();
  }
#undef STAGE_A
#undef STAGE_B
#undef RD_A
#undef RD_B
#undef MFMA_QPAIR

#pragma unroll
  for (int i = 0; i < 4; ++i) {
    const int rbase = m0 + wr * 64 + i * 16 + (quad << 2);
#pragma unroll
    for (int j = 0; j < 4; ++j) {
      const int col = n0 + wc * 64 + j * 16 + frow;
#pragma unroll
      for (int rg = 0; rg < 4; ++rg)
        Cp[(size_t)ks * pstride + (size_t)(rbase + rg) * N + col] = f2bf_bits(acc[i][j][rg]);
    }
  }
}

// ---------------- 256x256 MFMA GEMM, 64x128 wave tiles, KS=8 (v8 primary) -------------------
// R7 analysis: gemm is LDS-pipe-bound; per-FLOP LDS traffic set by wave-tile shape
// ((WM+WN)/(WM*WN)). 64x128 tiles (8 waves = 4M x 2N on a 256x256 block) cut LDS bytes
// per FLOP 27% vs 64x64: per-tile-per-CU LDS ~256KB (~2000-3000cyc) vs MFMA 2480cyc ->
// near 1:1. Grid (16,2,8)=256 blocks (1/CU) requires KS=8 (ypart 32MB; host gates on
// workspace and falls back to gemm_8ph). Schedule is the proven v4 merged pattern:
// stage in Ph0/Ph2, seal one full phase later (vmcnt(0)+barrier at Ph1/Ph3 end),
// lgkm(0)+sched_barrier per phase, setprio around MFMA. B-frag registers reused across
// the two column halves (compiler SSA keeps it correct). Per-acc K-order ascending;
// bf16 partial rounding at C-write; KS=8 partial error ~KS-invariant (m ~ 1/sqrt(KS),
// RSS ~ sqrt(KS)).
__global__ __launch_bounds__(512, 2) void gemm256(const u16* __restrict__ A,
                                                  const u16* __restrict__ B,
                                                  u16* __restrict__ Cp, size_t pstride, int N,
                                                  int Ktot) {
  extern __shared__ u16 smem[];
  u16* sA = smem;          // [2][256*64]
  u16* sB = smem + 32768;  // [2][256*64]
  const int tid = threadIdx.x;
  const int wave = tid >> 6;
  const int lane = tid & 63;
  const int wr = wave >> 1;  // 0..3 -> 64-row group
  const int wc = wave & 1;   // 0..1 -> 128-col group
  const int m0 = blockIdx.x * 256;
  const int n0 = blockIdx.y * 256;
  const int ks = blockIdx.z;
  const int Kper = Ktot / gridDim.z;  // 1024 at KS=8
  const int kb = ks * Kper;
  const int NITER = Kper >> 7;  // 8
  const int r_l = tid >> 3;
  const int g8 = (tid & 7) << 3;
  const int frow = lane & 15;
  const int quad = lane >> 4;
  const int sw = frow & 7;
  const int o0 = (quad ^ sw) << 3;
  const int o1 = ((4 | quad) ^ sw) << 3;

  const u16* Abase = A + (size_t)(m0 + r_l) * Ktot + g8;
  const u16* Bbase = B + (size_t)(n0 + r_l) * Ktot + g8;

#define STAGE_A(l, k0, b) \
  gl_lds16(Abase + (size_t)(l) * 64 * Ktot + (k0), sA + (b)*16384 + (l)*4096 + wave * 512)
#define STAGE_B(l, k0, b) \
  gl_lds16(Bbase + (size_t)(l) * 64 * Ktot + (k0), sB + (b)*16384 + (l)*4096 + wave * 512)
#define STAGE8(k0, b)    \
  do {                   \
    STAGE_A(0, k0, b);   \
    STAGE_A(1, k0, b);   \
    STAGE_A(2, k0, b);   \
    STAGE_A(3, k0, b);   \
    STAGE_B(0, k0, b);   \
    STAGE_B(1, k0, b);   \
    STAGE_B(2, k0, b);   \
    STAGE_B(3, k0, b);   \
  } while (0)
// 8x ds_read_b128: A frags (4 m-frags x kk=0,1) for this wave's 64 rows
#define RD_A8(b)                                                  \
  do {                                                            \
    const u16* _p = sA + (b)*16384 + (wr * 64 + frow) * 64;       \
    _Pragma("unroll") for (int f = 0; f < 4; ++f) {               \
      af[f][0] = *(const short8*)(_p + f * 1024 + o0);            \
      af[f][1] = *(const short8*)(_p + f * 1024 + o1);            \
    }                                                             \
  } while (0)
// 8x ds_read_b128: B frags (4 n-frags x kk) for col-half h (0: cols 0..63, 1: 64..127)
#define RD_B8(b, h)                                                         \
  do {                                                                      \
    const u16* _p = sB + (b)*16384 + (wc * 128 + (h)*64 + frow) * 64;       \
    _Pragma("unroll") for (int g = 0; g < 4; ++g) {                         \
      bf[g][0] = *(const short8*)(_p + g * 1024 + o0);                      \
      bf[g][1] = *(const short8*)(_p + g * 1024 + o1);                      \
    }                                                                       \
  } while (0)
// 32 MFMA: 4 m-frags x 4 n-frags (col-half h) x kk ascending
#define MFMA_H(h)                                                                   \
  do {                                                                              \
    _Pragma("unroll") for (int f = 0; f < 4; ++f)                                   \
        _Pragma("unroll") for (int g = 0; g < 4; ++g)                               \
            _Pragma("unroll") for (int kk = 0; kk < 2; ++kk) acc[f][(h)*4 + g] =    \
                __builtin_amdgcn_mfma_f32_16x16x32_bf16(af[f][kk], bf[g][kk],       \
                                                        acc[f][(h)*4 + g], 0, 0, 0); \
  } while (0)

  f32x4 acc[4][8];
#pragma unroll
  for (int i = 0; i < 4; ++i)
#pragma unroll
    for (int j = 0; j < 8; ++j) acc[i][j] = (f32x4){0.f, 0.f, 0.f, 0.f};

  short8 af[4][2];  // A frags, current tile (persist across the two halves)
  short8 bf[4][2];  // B frags, current col-half (reused between halves)

  // Prologue: stage tile0 -> b0, seal.
  STAGE8(kb, 0);
  asm volatile("s_waitcnt vmcnt(0)" ::: "memory");
  __builtin_amdgcn_s_barrier();

  for (int I = 0; I < NITER; ++I) {
    const int k0e = kb + (I << 7);
    const bool nl = (I < NITER - 1);

    // ---- Ph0: even tile (b0), col-half 0; stage odd tile -> b1 ----
    RD_A8(0);
    RD_B8(0, 0);
    STAGE8(k0e + 64, 1);  // b1's last reads drained before prev Ph3's trailing barrier
    __builtin_amdgcn_s_barrier();
    asm volatile("s_waitcnt lgkmcnt(0)" ::: "memory");
    __builtin_amdgcn_sched_barrier(0);
    __builtin_amdgcn_s_setprio(1);
    MFMA_H(0);
    __builtin_amdgcn_s_setprio(0);
    __builtin_amdgcn_s_barrier();

    // ---- Ph1: even tile (b0), col-half 1 ----
    RD_B8(0, 1);
    __builtin_amdgcn_s_barrier();
    asm volatile("s_waitcnt lgkmcnt(0)" ::: "memory");
    __builtin_amdgcn_sched_barrier(0);
    __builtin_amdgcn_s_setprio(1);
    MFMA_H(1);
    __builtin_amdgcn_s_setprio(0);
    asm volatile("s_waitcnt vmcnt(0)" ::: "memory");  // seal b1 (staged Ph0, ~1.5-phase slack)
    __builtin_amdgcn_s_barrier();

    // ---- Ph2: odd tile (b1), col-half 0; stage next even -> b0 ----
    RD_A8(1);
    RD_B8(1, 0);
    if (nl) STAGE8(k0e + 128, 0);  // b0's last reads drained before Ph1's trailing barrier
    __builtin_amdgcn_s_barrier();
    asm volatile("s_waitcnt lgkmcnt(0)" ::: "memory");
    __builtin_amdgcn_sched_barrier(0);
    __builtin_amdgcn_s_setprio(1);
    MFMA_H(0);
    __builtin_amdgcn_s_setprio(0);
    __builtin_amdgcn_s_barrier();

    // ---- Ph3: odd tile (b1), col-half 1 ----
    RD_B8(1, 1);
    __builtin_amdgcn_s_barrier();
    asm volatile("s_waitcnt lgkmcnt(0)" ::: "memory");
    __builtin_amdgcn_sched_barrier(0);
    __builtin_amdgcn_s_setprio(1);
    MFMA_H(1);
    __builtin_amdgcn_s_setprio(0);
    if (nl) asm volatile("s_waitcnt vmcnt(0)" ::: "memory");  // seal b0 (staged Ph2)
    __builtin_amdgcn_s_barrier();
  }
#undef STAGE_A
#undef STAGE_B
#undef STAGE8
#undef RD_A8
#undef RD_B8
#undef MFMA_H

#pragma unroll
  for (int i = 0; i < 4; ++i) {
    const int rbase = m0 + wr * 64 + i * 16 + (quad << 2);
#pragma unroll
    for (int j = 0; j < 8; ++j) {
      const int col = n0 + wc * 128 + j * 16 + frow;
#pragma unroll
      for (int rg = 0; rg < 4; ++rg)
        Cp[(size_t)ks * pstride + (size_t)(rbase + rg) * N + col] = f2bf_bits(acc[i][j][rg]);
    }
  }
}

// ---------------- p/q prep: pT=|tr| transposed, q=|ct|/(1e-8+Sp*Sq) ----------------
__global__ void prep_pq(const float* __restrict__ trct, float* __restrict__ pT,
                        float* __restrict__ q) {
  int t = blockIdx.x;
  int lane = threadIdx.x;  // 64
  float tr = trct[t * 128 + lane];
  float ct = trct[t * 128 + 64 + lane];
  float ap = fabsf(tr), aq = fabsf(ct);
  float Sp = wave_sum(ap);
  float Sq = wave_sum(aq);
  float denom = 1e-8f + Sp * Sq;
  pT[lane * T_LEN + t] = ap;  // transposed for shuffle-broadcast in scans
  q[t * 64 + lane] = aq / denom;
}

// ---------------- scan phase 1: per-chunk affine summary (A,B) ----------------
__global__ void scan_phase1(const float* __restrict__ pT, const float* __restrict__ q,
                            const unsigned char* __restrict__ st8, const int* __restrict__ st32,
                            const int* __restrict__ modep, const float* __restrict__ a,
                            const float* __restrict__ b, float4* __restrict__ chunkbuf) {
  int chunk = blockIdx.x, r = blockIdx.y, c = threadIdx.x;
  int mode = modep[0];
  int t0 = chunk * CLEN;
  float na = -fabsf(a[r]);
  float rho = __expf(na);
  float bb = b[c];
  float er = rho * __cosf(bb), ei = rho * __sinf(bb);
  float pv = pT[r * T_LEN + t0 + c];             // lane c holds p for step c
  int sv = read_start(st8, st32, mode, t0 + c);  // lane c holds start for step c
  unsigned long long bal = __ballot(sv != 0);
  float Ar, Ai;
  if (bal) {
    Ar = 0.f; Ai = 0.f;
  } else {
    float mag = __expf(64.f * na);
    float ang = 64.f * bb;
    Ar = mag * __cosf(ang);
    Ai = mag * __sinf(ang);
  }
  int L = bal ? (63 - __builtin_clzll(bal)) : 0;  // wave-uniform
  float Br = 0.f, Bi = 0.f;
  const float* qrow = q + (size_t)t0 * 64 + c;
  for (int i = L; i < CLEN; ++i) {
    float pre = __shfl(pv, i) * qrow[i * 64];
    float nBr = er * Br - ei * Bi + pre;
    Bi = er * Bi + ei * Br;
    Br = nBr;
  }
  chunkbuf[((size_t)chunk * 64 + r) * 64 + c] = make_float4(Ar, Ai, Br, Bi);
}

// ---------------- scan phase 2: sequential chunk combine ----------------
__global__ void scan_phase2(const float4* __restrict__ chunkbuf, const float* __restrict__ state,
                            float2* __restrict__ s0buf) {
  int r = blockIdx.x, c = threadIdx.x;
  float Sr = state[r * 64 + c], Si = 0.f;
  for (int k = 0; k < NCHUNK; ++k) {
    s0buf[((size_t)k * 64 + r) * 64 + c] = make_float2(Sr, Si);
    float4 ab = chunkbuf[((size_t)k * 64 + r) * 64 + c];
    float nSr = ab.x * Sr - ab.y * Si + ab.z;
    Si = ab.x * Si + ab.y * Sr + ab.w;
    Sr = nSr;
  }
}

// ---------------- scan phase 3: replay + packed log-polar features (swizzled store) ----
__global__ void scan_phase3(const float* __restrict__ pT, const float* __restrict__ q,
                            const unsigned char* __restrict__ st8, const int* __restrict__ st32,
                            const int* __restrict__ modep, const float* __restrict__ a,
                            const float* __restrict__ b, const float2* __restrict__ s0buf,
                            u32* __restrict__ scaled, int c0) {
  int chunk = c0 + blockIdx.x, r = blockIdx.y, c = threadIdx.x;
  int mode = modep[0];
  int t0 = chunk * CLEN;
  float rho = __expf(-fabsf(a[r]));
  float bb = b[c];
  float er = rho * __cosf(bb), ei = rho * __sinf(bb);
  float pv = pT[r * T_LEN + t0 + c];
  int sv = read_start(st8, st32, mode, t0 + c);
  float2 s0 = s0buf[((size_t)chunk * 64 + r) * 64 + c];
  float Sr = s0.x, Si = s0.y;
  int tl0 = (chunk - c0) * CLEN;
  const float* qrow = q + (size_t)t0 * 64 + c;
  u32* srow = scaled + (size_t)tl0 * 4096;
  const int Ldw = r * 64 + c;
#pragma unroll 4
  for (int i = 0; i < CLEN; ++i) {
    float qt = qrow[i * 64];
    float pt = __shfl(pv, i);
    int st = __shfl(sv, i);
    float pre = pt * qt;
    float cer = st ? 0.f : er;
    float cei = st ? 0.f : ei;
    float nSr = cer * Sr - cei * Si + pre;
    Si = cer * Si + cei * Sr;
    Sr = nSr;
    float m2 = fmaf(Sr, Sr, Si * Si);
    float rsq = rsqrtf(fmaxf(m2, 1e-30f));
    float m = m2 * rsq;
    float sc = __log2f(1.0f + m) * 0.6931471805599453f * rsq;
    u32 pack = ((u32)f2bf_bits(sc * Sr) << 16) | (u32)f2bf_bits(sc * Si);
    srow[(size_t)i * 4096 + (Ldw ^ ((i & 7) << 2))] = pack;
  }
}

// ---------------- LN + LeakyReLU over bf16 split-K partials -> z0bf (vectorized, 1 wave/row) ----
__global__ void ln_act16(const u16* __restrict__ parts, int KS, size_t pstride,
                         const float* __restrict__ bias, const float* __restrict__ gam,
                         const float* __restrict__ bet, u16* __restrict__ zbf) {
  int t = blockIdx.x, lane = threadIdx.x;  // 64 lanes
  int e0 = lane << 3;
  size_t o = (size_t)t * D_DIM + e0;
  float4 ba = *(const float4*)(bias + e0);
  float4 bb4 = *(const float4*)(bias + e0 + 4);
  float v[8] = {ba.x, ba.y, ba.z, ba.w, bb4.x, bb4.y, bb4.z, bb4.w};
  for (int ks = 0; ks < KS; ++ks) {
    short8 p = *(const short8*)(parts + (size_t)ks * pstride + o);
#pragma unroll
    for (int j = 0; j < 8; ++j) v[j] += bf2f((u16)p[j]);
  }
  float s8 = 0.f;
#pragma unroll
  for (int j = 0; j < 8; ++j) s8 += v[j];
  float mean = wave_sum(s8) * (1.f / 512.f);
  float d[8];
  float sq = 0.f;
#pragma unroll
  for (int j = 0; j < 8; ++j) {
    d[j] = v[j] - mean;
    sq = fmaf(d[j], d[j], sq);
  }
  float var = wave_sum(sq) * (1.f / 512.f);
  float rstd = rsqrtf(var + 1e-5f);
  float4 g0v = *(const float4*)(gam + e0);
  float4 g1v = *(const float4*)(gam + e0 + 4);
  float4 t0v = *(const float4*)(bet + e0);
  float4 t1v = *(const float4*)(bet + e0 + 4);
  float gg[8] = {g0v.x, g0v.y, g0v.z, g0v.w, g1v.x, g1v.y, g1v.z, g1v.w};
  float tt[8] = {t0v.x, t0v.y, t0v.z, t0v.w, t1v.x, t1v.y, t1v.z, t1v.w};
  short8 r;
#pragma unroll
  for (int j = 0; j < 8; ++j) {
    float z = d[j] * rstd * gg[j] + tt[j];
    z = z > 0.f ? z : 0.01f * z;
    r[j] = (short)f2bf_bits(z);
  }
  *(short8*)(zbf + o) = r;
}

// ---------------- LN + LeakyReLU over fp32 y (W1 epilogue; vectorized, 1 wave/row) ----------
__global__ void ln_act32(const float* __restrict__ y, const float* __restrict__ bias,
                         const float* __restrict__ gam, const float* __restrict__ bet,
                         const float* __restrict__ xsrc, float* __restrict__ xdst,
                         u16* __restrict__ xbf_next, float* __restrict__ finout) {
  int t = blockIdx.x, lane = threadIdx.x;  // 64 lanes
  int e0 = lane << 3;
  size_t o = (size_t)t * D_DIM + e0;
  float4 y0 = *(const float4*)(y + o);
  float4 y1 = *(const float4*)(y + o + 4);
  float4 ba = *(const float4*)(bias + e0);
  float4 bb4 = *(const float4*)(bias + e0 + 4);
  float v[8] = {y0.x + ba.x, y0.y + ba.y, y0.z + ba.z, y0.w + ba.w,
                y1.x + bb4.x, y1.y + bb4.y, y1.z + bb4.z, y1.w + bb4.w};
  float s8 = 0.f;
#pragma unroll
  for (int j = 0; j < 8; ++j) s8 += v[j];
  float mean = wave_sum(s8) * (1.f / 512.f);
  float d[8];
  float sq = 0.f;
#pragma unroll
  for (int j = 0; j < 8; ++j) {
    d[j] = v[j] - mean;
    sq = fmaf(d[j], d[j], sq);
  }
  float var = wave_sum(sq) * (1.f / 512.f);
  float rstd = rsqrtf(var + 1e-5f);
  float4 g0v = *(const float4*)(gam + e0);
  float4 g1v = *(const float4*)(gam + e0 + 4);
  float4 t0v = *(const float4*)(bet + e0);
  float4 t1v = *(const float4*)(bet + e0 + 4);
  float gg[8] = {g0v.x, g0v.y, g0v.z, g0v.w, g1v.x, g1v.y, g1v.z, g1v.w};
  float tt[8] = {t0v.x, t0v.y, t0v.z, t0v.w, t1v.x, t1v.y, t1v.z, t1v.w};
  float z[8];
#pragma unroll
  for (int j = 0; j < 8; ++j) {
    float zz = d[j] * rstd * gg[j] + tt[j];
    z[j] = zz > 0.f ? zz : 0.01f * zz;
  }
  if (xdst) {
    float4 x0 = *(const float4*)(xsrc + o);
    float4 x1 = *(const float4*)(xsrc + o + 4);
    float xx[8] = {x0.x + z[0], x0.y + z[1], x0.z + z[2], x0.w + z[3],
                   x1.x + z[4], x1.y + z[5], x1.z + z[6], x1.w + z[7]};
    *(float4*)(xdst + o) = make_float4(xx[0], xx[1], xx[2], xx[3]);
    *(float4*)(xdst + o + 4) = make_float4(xx[4], xx[5], xx[6], xx[7]);
    short8 r;
#pragma unroll
    for (int j = 0; j < 8; ++j) r[j] = (short)f2bf_bits(xx[j]);
    *(short8*)(xbf_next + o) = r;
  }
  if (finout) {
    *(float4*)(finout + o) = make_float4(z[0], z[1], z[2], z[3]);
    *(float4*)(finout + o + 4) = make_float4(z[4], z[5], z[6], z[7]);
  }
}

__global__ void err_signal(float* __restrict__ out, float code) {
  if (threadIdx.x == 0) out[0] = code;
}

// ---------------- host launch ----------------
extern "C" void kernel_launch(void* const* d_in, const int* in_sizes, int n_in, void* d_out,
                              int out_size, void* d_ws, size_t ws_size, hipStream_t stream) {
  const float* x_in = (const float*)d_in[0];
  const float* state = (const float*)d_in[1];
  const unsigned char* start8 = (const unsigned char*)d_in[2];
  const int* start32 = (const int*)d_in[2];
  const float* Wtr = (const float*)d_in[3];
  const float* Wc = (const float*)d_in[4];
  const float* a_in = (const float*)d_in[5];
  const float* b_in = (const float*)d_in[6];
  const float* W0 = (const float*)d_in[7];
  const float* b0 = (const float*)d_in[8];
  const float* g0 = (const float*)d_in[9];
  const float* beta0 = (const float*)d_in[10];
  const float* W1 = (const float*)d_in[11];
  const float* b1 = (const float*)d_in[12];
  const float* g1 = (const float*)d_in[13];
  const float* beta1 = (const float*)d_in[14];
  float* out = (float*)d_out;

  // one-time: allow 96 KiB / 128 KiB dynamic LDS for the GEMMs
  static int attr_state = 0;  // 0 unset, 1 ok, -1 failed
  if (attr_state == 0)
    attr_state = (hipFuncSetAttribute((const void*)gemm_8ph,
                                      hipFuncAttributeMaxDynamicSharedMemorySize,
                                      98304) == hipSuccess)
                     ? 1
                     : -1;
  static int attr256_state = 0;
  if (attr256_state == 0)
    attr256_state = (hipFuncSetAttribute((const void*)gemm256,
                                         hipFuncAttributeMaxDynamicSharedMemorySize,
                                         131072) == hipSuccess)
                        ? 1
                        : -1;
  const bool attr_ok = (attr_state == 1);
  const bool attr256_ok = (attr256_state == 1);

  char* w = (char*)d_ws;
  auto alloc = [&](size_t bytes) {
    char* ptr = w;
    w += (bytes + 255) & ~(size_t)255;
    return ptr;
  };
  float* x_ws = (float*)alloc(4ull * T_LEN * D_DIM);            // 8 MB
  u16* xbf = (u16*)alloc(2ull * T_LEN * D_DIM);                 // 4 MB
  u16* wcat = (u16*)alloc(2ull * 128 * D_DIM);                  // 128 KB
  u16* w0bf = (u16*)alloc(2ull * D_DIM * F_DIM);                // 8 MB (per-layer)
  u16* w1bf = (u16*)alloc(2ull * 3 * D_DIM * D_DIM);            // 1.5 MB (all layers)
  float* trct = (float*)alloc(4ull * T_LEN * 128);              // 2 MB
  float* pTbuf = (float*)alloc(4ull * T_LEN * 64);              // 1 MB
  float* qbuf = (float*)alloc(4ull * T_LEN * 64);               // 1 MB
  float4* chunkbuf = (float4*)alloc(16ull * NCHUNK * 64 * 64);  // 4 MB
  float2* s0buf = (float2*)alloc(8ull * NCHUNK * 64 * 64);      // 2 MB
  u16* z0bf = (u16*)alloc(2ull * T_LEN * D_DIM);                // 4 MB
  float* ybuf = (float*)alloc(4ull * T_LEN * D_DIM);            // 8 MB (W1 out)
  int* modep = (int*)alloc(256);
  size_t base1 = (size_t)(w - (char*)d_ws);

  if (n_in != 15) {
    err_signal<<<1, 64, 0, stream>>>(out, 9e6f + 1000.f * n_in);
    return;
  }
  const size_t MB = 1ull << 20;
  const size_t pstride = (size_t)T_LEN * D_DIM;  // elements per partial slab
  int KS, nseg, use256 = 0;
  if (ws_size >= base1 + 32 * MB + 64 * MB && attr256_ok) { KS = 8; nseg = 1; use256 = 1; }
  else if (ws_size >= base1 + 16 * MB + 64 * MB) { KS = 4; nseg = 1; }
  else if (ws_size >= base1 + 16 * MB + 32 * MB) { KS = 4; nseg = 2; }
  else if (ws_size >= base1 + 8 * MB + 32 * MB) { KS = 2; nseg = 2; }
  else if (ws_size >= base1 + 8 * MB + 16 * MB) { KS = 2; nseg = 4; }
  else if (ws_size >= base1 + 4 * MB + 16 * MB) { KS = 1; nseg = 4; }
  else {
    err_signal<<<1, 64, 0, stream>>>(out, 9e6f);
    return;
  }
  const int seg_rows = T_LEN / nseg;
  const int seg_chunks = NCHUNK / nseg;
  u16* ypart = (u16*)alloc(2ull * KS * pstride);
  u16* scaled = (u16*)alloc(2ull * seg_rows * F_DIM);

  const bool use8 = (nseg == 1) && attr_ok && !use256;

  detect_start<<<1, 256, 0, stream>>>(start8, modep);
  f2bf<<<(T_LEN * D_DIM) / 256, 256, 0, stream>>>(x_in, xbf, T_LEN * D_DIM);
  f2bf<<<(3 * D_DIM * D_DIM) / 256, 256, 0, stream>>>(W1, w1bf, 3 * D_DIM * D_DIM);

  for (int l = 0; l < 3; ++l) {
    const float* Wtr_l = Wtr + (size_t)l * 64 * D_DIM;
    const float* Wc_l = Wc + (size_t)l * 64 * D_DIM;
    const float* a_l = a_in + l * 64;
    const float* b_l = b_in + l * 64;
    const float* W0_l = W0 + (size_t)l * D_DIM * F_DIM;
    const u16* w1bf_l = w1bf + (size_t)l * D_DIM * D_DIM;
    const float* state_l = state + (size_t)l * 64 * 64;
    const float* xsrc = (l == 0) ? x_in : x_ws;

    k_conv<<<(128 * D_DIM + D_DIM * F_DIM) / 256, 256, 0, stream>>>(Wtr_l, Wc_l, wcat, W0_l,
                                                                    w0bf);
    // trct (4096 x 128) = xbf @ wcat^T
    gemm_bt<64, 64, 2, 2><<<dim3(T_LEN / 64, 2), 256, 0, stream>>>(xbf, wcat, trct, T_LEN, 128,
                                                                   D_DIM);
    prep_pq<<<T_LEN, 64, 0, stream>>>(trct, pTbuf, qbuf);
    scan_phase1<<<dim3(NCHUNK, 64), 64, 0, stream>>>(pTbuf, qbuf, start8, start32, modep, a_l,
                                                     b_l, chunkbuf);
    scan_phase2<<<64, 64, 0, stream>>>(chunkbuf, state_l, s0buf);

    for (int h = 0; h < nseg; ++h) {
      scan_phase3<<<dim3(seg_chunks, 64), 64, 0, stream>>>(pTbuf, qbuf, start8, start32, modep,
                                                           a_l, b_l, s0buf, (u32*)scaled,
                                                           h * seg_chunks);
      if (use256)
        gemm256<<<dim3(seg_rows / 256, D_DIM / 256, KS), 512, 131072, stream>>>(
            scaled, w0bf, ypart + (size_t)h * seg_rows * D_DIM, pstride, D_DIM, F_DIM);
      else if (use8)
        gemm_8ph<<<dim3(seg_rows / 256, D_DIM / 128, KS), 512, 98304, stream>>>(
            scaled, w0bf, ypart + (size_t)h * seg_rows * D_DIM, pstride, D_DIM, F_DIM);
      else
        gemm128<<<dim3(seg_rows / 128, D_DIM / 128, KS), 256, 0, stream>>>(
            scaled, w0bf, ypart + (size_t)h * seg_rows * D_DIM, pstride, D_DIM, F_DIM);
    }
    ln_act16<<<T_LEN, 64, 0, stream>>>(ypart, KS, pstride, b0 + l * D_DIM, g0 + l * D_DIM,
                                       beta0 + l * D_DIM, z0bf);
    // y2 = z0 (4096x512) @ W1 (512x512)^T — no split-K, grid 64x8 = 512 blocks
    gemm_bt<64, 64, 2, 2><<<dim3(T_LEN / 64, D_DIM / 64), 256, 0, stream>>>(z0bf, w1bf_l, ybuf,
                                                                            T_LEN, D_DIM, D_DIM);
    ln_act32<<<T_LEN, 64, 0, stream>>>(ybuf, b1 + l * D_DIM, g1 + l * D_DIM, beta1 + l * D_DIM,
                                       (l < 2) ? xsrc : nullptr, (l < 2) ? x_ws : nullptr,
                                       (l < 2) ? xbf : nullptr, (l == 2) ? out : nullptr);
  }
}

// Round 9
// 475.477 us; speedup vs baseline: 1.0480x; 1.0480x over previous
//
#include <hip/hip_runtime.h>
#include <hip/hip_bf16.h>
#include <math.h>

#define T_LEN 4096
#define D_DIM 512
#define F_DIM 8192
#define NCHUNK 64
#define CLEN 64

typedef short short8 __attribute__((ext_vector_type(8)));
typedef float f32x4 __attribute__((ext_vector_type(4)));
typedef unsigned short u16;
typedef unsigned int u32;

// ---------------- helpers ----------------
__device__ inline float wave_sum(float v) {
#pragma unroll
  for (int o = 32; o; o >>= 1) v += __shfl_xor(v, o);
  return v;
}

__device__ inline u16 f2bf_bits(float v) {
  __hip_bfloat16 h = __float2bfloat16(v);
  return *(u16*)&h;
}

__device__ inline float bf2f(u16 u) {
  u32 x = ((u32)u) << 16;
  return *(float*)&x;
}

__device__ inline void gl_lds16(const void* g, void* l) {
  __builtin_amdgcn_global_load_lds((const __attribute__((address_space(1))) void*)g,
                                   (__attribute__((address_space(3))) void*)l, 16, 0, 0);
}

// start[] may arrive as 1-byte bools or int32 {0,1}.
__global__ void detect_start(const unsigned char* __restrict__ s8, int* __restrict__ mode) {
  __shared__ int found;
  if (threadIdx.x == 0) found = 0;
  __syncthreads();
  for (int i = threadIdx.x; i < 4096; i += 256)
    if ((i & 3) && s8[i]) found = 1;  // benign race, same value
  __syncthreads();
  if (threadIdx.x == 0) mode[0] = found;  // 1 = byte layout, 0 = int32 layout
}

__device__ inline int read_start(const unsigned char* s8, const int* s32, int mode, int t) {
  return mode ? (int)s8[t] : s32[t];
}

// ---------------- fp32 -> bf16(bits) convert (plain) ----------------
__global__ void f2bf(const float* __restrict__ s, u16* __restrict__ d, int n) {
  int i = blockIdx.x * 256 + threadIdx.x;
  if (i < n) d[i] = f2bf_bits(s[i]);
}

// fused per-layer weight conversion:
//   wcat = concat [Wtr_l; Wc_l] (128 x 512), unswizzled (BK=32 gemm)
//   w0bf: K-permute (f = r*128+2c+b <- b*4096+r*64+c) + granule swizzle by (d&7)
__global__ void k_conv(const float* __restrict__ wtr, const float* __restrict__ wc,
                       u16* __restrict__ wcat, const float* __restrict__ w0,
                       u16* __restrict__ w0bf) {
  int i = blockIdx.x * 256 + threadIdx.x;
  if (i < 128 * D_DIM) {
    float v = (i < 64 * D_DIM) ? wtr[i] : wc[i - 64 * D_DIM];
    wcat[i] = f2bf_bits(v);
  }
  int j = i - 128 * D_DIM;
  if (j >= 0 && j < D_DIM * F_DIM) {
    int d = j >> 13, f = j & 8191;
    int r = f >> 7, rem = f & 127;
    int c = rem >> 1, b = rem & 1;
    float v = w0[(size_t)d * 8192 + b * 4096 + r * 64 + c];
    w0bf[(size_t)d * 8192 + (f ^ ((d & 7) << 3))] = f2bf_bits(v);
  }
}

// ---------------- small MFMA GEMM (64x64 tile, BK=32, sync staging) — trct & W1 ----------------
template <int BM, int BN, int WR, int WC>
__global__ __launch_bounds__(256) void gemm_bt(const u16* __restrict__ A,
                                               const u16* __restrict__ B,
                                               float* __restrict__ C, int M, int N, int K) {
  constexpr int BK = 32;
  constexpr int MT = BM / (WR * 16);
  constexpr int NT = BN / (WC * 16);
  constexpr int AG = BM / 64;
  constexpr int BG = BN / 64;
  __shared__ u16 sA[BM * BK];
  __shared__ u16 sB[BN * BK];
  const int m0 = blockIdx.x * BM;
  const int n0 = blockIdx.y * BN;
  const int tid = threadIdx.x;
  const int wave = tid >> 6;
  const int lane = tid & 63;
  const int wr = wave / WC;
  const int wc = wave % WC;
  const int row_l = tid >> 2;
  const int c8 = (tid & 3) << 3;
  const int frow = lane & 15;
  const int fcol = (lane >> 4) << 3;

  f32x4 acc[MT][NT];
#pragma unroll
  for (int i = 0; i < MT; ++i)
#pragma unroll
    for (int j = 0; j < NT; ++j) acc[i][j] = (f32x4){0.f, 0.f, 0.f, 0.f};

  for (int k0 = 0; k0 < K; k0 += BK) {
#pragma unroll
    for (int j = 0; j < AG; ++j) {
      uint4 v = *(const uint4*)(A + (size_t)(m0 + j * 64 + row_l) * K + (k0 + c8));
      *(uint4*)(sA + (j * 64 + row_l) * BK + c8) = v;
    }
#pragma unroll
    for (int j = 0; j < BG; ++j) {
      uint4 v = *(const uint4*)(B + (size_t)(n0 + j * 64 + row_l) * K + (k0 + c8));
      *(uint4*)(sB + (j * 64 + row_l) * BK + c8) = v;
    }
    __syncthreads();
    short8 af[MT], bfr[NT];
#pragma unroll
    for (int i = 0; i < MT; ++i)
      af[i] = *(const short8*)(sA + (wr * MT * 16 + i * 16 + frow) * BK + fcol);
#pragma unroll
    for (int j = 0; j < NT; ++j)
      bfr[j] = *(const short8*)(sB + (wc * NT * 16 + j * 16 + frow) * BK + fcol);
#pragma unroll
    for (int i = 0; i < MT; ++i)
#pragma unroll
      for (int j = 0; j < NT; ++j)
        acc[i][j] = __builtin_amdgcn_mfma_f32_16x16x32_bf16(af[i], bfr[j], acc[i][j], 0, 0, 0);
    __syncthreads();
  }
#pragma unroll
  for (int i = 0; i < MT; ++i) {
    const int rbase = m0 + wr * MT * 16 + i * 16 + ((lane >> 4) << 2);
#pragma unroll
    for (int j = 0; j < NT; ++j) {
      const int col = n0 + wc * NT * 16 + j * 16 + (lane & 15);
#pragma unroll
      for (int rg = 0; rg < 4; ++rg) C[(size_t)(rbase + rg) * N + col] = acc[i][j][rg];
    }
  }
}

// ---------------- 128x128 MFMA GEMM, BK=64, XOR-swizzled operands, split-K, bf16 partials ----
// (retained for low-workspace fallback paths)
// A, B global layout: row-major with 16B granule g of each row stored at g ^ (row&7).
__global__ __launch_bounds__(256) void gemm128(const u16* __restrict__ A,
                                               const u16* __restrict__ B,
                                               u16* __restrict__ Cp, size_t pstride, int N,
                                               int Ktot) {
  __shared__ u16 sA[128 * 64];
  __shared__ u16 sB[128 * 64];
  const int tid = threadIdx.x;
  const int wave = tid >> 6;
  const int lane = tid & 63;
  const int wr = wave >> 1;
  const int wc = wave & 1;
  const int m0 = blockIdx.x * 128;
  const int n0 = blockIdx.y * 128;
  const int ks = blockIdx.z;
  const int Kper = Ktot / gridDim.z;
  const int kb = ks * Kper;
  const int row_s = tid >> 3;     // 0..31 staging row within 32-row group
  const int g8 = (tid & 7) << 3;  // granule offset (elems)
  const int frow = lane & 15;
  const int quad = lane >> 4;
  const int sw = frow & 7;

  f32x4 acc[4][4];
#pragma unroll
  for (int i = 0; i < 4; ++i)
#pragma unroll
    for (int j = 0; j < 4; ++j) acc[i][j] = (f32x4){0.f, 0.f, 0.f, 0.f};

  for (int k0 = kb; k0 < kb + Kper; k0 += 64) {
#pragma unroll
    for (int j = 0; j < 4; ++j) {
      gl_lds16(A + (size_t)(m0 + j * 32 + row_s) * Ktot + (k0 + g8), sA + j * 2048 + wave * 512);
      gl_lds16(B + (size_t)(n0 + j * 32 + row_s) * Ktot + (k0 + g8), sB + j * 2048 + wave * 512);
    }
    asm volatile("s_waitcnt vmcnt(0)" ::: "memory");
    __syncthreads();
#pragma unroll
    for (int kk = 0; kk < 2; ++kk) {
      const int gA = (((kk << 2) | quad) ^ sw) << 3;  // swizzled elem offset in row
      short8 af[4], bfr[4];
#pragma unroll
      for (int i = 0; i < 4; ++i)
        af[i] = *(const short8*)(sA + (wr * 64 + i * 16 + frow) * 64 + gA);
#pragma unroll
      for (int j = 0; j < 4; ++j)
        bfr[j] = *(const short8*)(sB + (wc * 64 + j * 16 + frow) * 64 + gA);
#pragma unroll
      for (int i = 0; i < 4; ++i)
#pragma unroll
        for (int j = 0; j < 4; ++j)
          acc[i][j] = __builtin_amdgcn_mfma_f32_16x16x32_bf16(af[i], bfr[j], acc[i][j], 0, 0, 0);
    }
    __syncthreads();
  }
#pragma unroll
  for (int i = 0; i < 4; ++i) {
    const int rbase = m0 + wr * 64 + i * 16 + ((lane >> 4) << 2);
#pragma unroll
    for (int j = 0; j < 4; ++j) {
      const int col = n0 + wc * 64 + j * 16 + (lane & 15);
#pragma unroll
      for (int rg = 0; rg < 4; ++rg)
        Cp[(size_t)ks * pstride + (size_t)(rbase + rg) * N + col] = f2bf_bits(acc[i][j][rg]);
    }
  }
}

// ---------------- 256x128 MFMA GEMM, merged 4-phase counted pipeline (fallback; 42us) ---------
// Proven v4 structure. See R4/R7 notes. KS=4 path.
__global__ __launch_bounds__(512, 2) void gemm_8ph(const u16* __restrict__ A,
                                                   const u16* __restrict__ B,
                                                   u16* __restrict__ Cp, size_t pstride, int N,
                                                   int Ktot) {
  extern __shared__ u16 smem[];
  u16* sA = smem;          // [2][256*64]
  u16* sB = smem + 32768;  // [2][128*64]
  const int tid = threadIdx.x;
  const int wave = tid >> 6;
  const int lane = tid & 63;
  const int wr = wave >> 1;  // 0..3 -> 64-row group
  const int wc = wave & 1;   // 0..1 -> 64-col group
  const int m0 = blockIdx.x * 256;
  const int n0 = blockIdx.y * 128;
  const int ks = blockIdx.z;
  const int Kper = Ktot / gridDim.z;
  const int kb = ks * Kper;
  const int NITER = Kper >> 7;  // 128 K per iteration (2 x BK=64 tiles)
  const int r_l = tid >> 3;     // row within 64-row load group
  const int g8 = (tid & 7) << 3;
  const int frow = lane & 15;
  const int quad = lane >> 4;
  const int sw = frow & 7;
  const int o0 = (quad ^ sw) << 3;        // swizzled elem offset, kk=0
  const int o1 = ((4 | quad) ^ sw) << 3;  // swizzled elem offset, kk=1

  const u16* Abase = A + (size_t)(m0 + r_l) * Ktot + g8;
  const u16* Bbase = B + (size_t)(n0 + r_l) * Ktot + g8;

#define STAGE_A(l, k0, b) \
  gl_lds16(Abase + (size_t)(l) * 64 * Ktot + (k0), sA + (b)*16384 + (l)*4096 + wave * 512)
#define STAGE_B(l, k0, b) \
  gl_lds16(Bbase + (size_t)(l) * 64 * Ktot + (k0), sB + (b)*8192 + (l)*4096 + wave * 512)
#define RD_A(dst, b, qm_)                                               \
  do {                                                                  \
    const u16* _p = sA + (b)*16384 + (wr * 64 + (qm_)*32 + frow) * 64;  \
    dst[0][0] = *(const short8*)(_p + o0);                              \
    dst[0][1] = *(const short8*)(_p + o1);                              \
    dst[1][0] = *(const short8*)(_p + 1024 + o0);                       \
    dst[1][1] = *(const short8*)(_p + 1024 + o1);                       \
  } while (0)
#define RD_B(dst, b, half_)                                              \
  do {                                                                   \
    const u16* _p = sB + (b)*8192 + (wc * 64 + (half_)*32 + frow) * 64;  \
    dst[0][0] = *(const short8*)(_p + o0);                               \
    dst[0][1] = *(const short8*)(_p + o1);                               \
    dst[1][0] = *(const short8*)(_p + 1024 + o0);                        \
    dst[1][1] = *(const short8*)(_p + 1024 + o1);                        \
  } while (0)
#define MFMA_QPAIR(ar, b0_, b1_, qm_)                                               \
  do {                                                                              \
    _Pragma("unroll") for (int f = 0; f < 2; ++f) _Pragma("unroll") for (int g = 0; \
                                                                         g < 2;    \
                                                                         ++g)      \
        _Pragma("unroll") for (int kk = 0; kk < 2; ++kk) acc[(qm_)*2 + f][g] =      \
            __builtin_amdgcn_mfma_f32_16x16x32_bf16(ar[f][kk], b0_[g][kk],          \
                                                    acc[(qm_)*2 + f][g], 0, 0, 0); \
    _Pragma("unroll") for (int f = 0; f < 2; ++f) _Pragma("unroll") for (int g = 0; \
                                                                         g < 2;    \
                                                                         ++g)      \
        _Pragma("unroll") for (int kk = 0; kk < 2; ++kk) acc[(qm_)*2 + f][2 + g] =  \
            __builtin_amdgcn_mfma_f32_16x16x32_bf16(ar[f][kk], b1_[g][kk],          \
                                                    acc[(qm_)*2 + f][2 + g], 0, 0,  \
                                                    0);                             \
  } while (0)

  f32x4 acc[4][4];
#pragma unroll
  for (int i = 0; i < 4; ++i)
#pragma unroll
    for (int j = 0; j < 4; ++j) acc[i][j] = (f32x4){0.f, 0.f, 0.f, 0.f};

  short8 af_lo[2][2];
  short8 af_hi[2][2];
  short8 bfr0[2][2];
  short8 bfr1[2][2];

  STAGE_A(0, kb, 0);
  STAGE_A(1, kb, 0);
  STAGE_A(2, kb, 0);
  STAGE_A(3, kb, 0);
  STAGE_B(0, kb, 0);
  STAGE_B(1, kb, 0);
  asm volatile("s_waitcnt vmcnt(0)" ::: "memory");
  __builtin_amdgcn_s_barrier();

  for (int I = 0; I < NITER; ++I) {
    const int k0e = kb + (I << 7);
    const bool nl = (I < NITER - 1);

    // ---- P0 ----
    RD_A(af_lo, 0, 0);
    RD_B(bfr0, 0, 0);
    RD_B(bfr1, 0, 1);
    STAGE_A(0, k0e + 64, 1);
    STAGE_A(1, k0e + 64, 1);
    STAGE_A(2, k0e + 64, 1);
    STAGE_A(3, k0e + 64, 1);
    STAGE_B(0, k0e + 64, 1);
    STAGE_B(1, k0e + 64, 1);
    __builtin_amdgcn_s_barrier();
    asm volatile("s_waitcnt lgkmcnt(0)" ::: "memory");
    __builtin_amdgcn_sched_barrier(0);
    __builtin_amdgcn_s_setprio(1);
    MFMA_QPAIR(af_lo, bfr0, bfr1, 0);
    __builtin_amdgcn_s_setprio(0);
    __builtin_amdgcn_s_barrier();

    // ---- P1 ----
    RD_A(af_hi, 0, 1);
    __builtin_amdgcn_s_barrier();
    asm volatile("s_waitcnt lgkmcnt(0)" ::: "memory");
    __builtin_amdgcn_sched_barrier(0);
    __builtin_amdgcn_s_setprio(1);
#pragma unroll
    for (int f = 0; f < 2; ++f)
#pragma unroll
      for (int g = 0; g < 2; ++g)
#pragma unroll
        for (int kk = 0; kk < 2; ++kk)
          acc[2 + f][2 + g] = __builtin_amdgcn_mfma_f32_16x16x32_bf16(
              af_hi[f][kk], bfr1[g][kk], acc[2 + f][2 + g], 0, 0, 0);
#pragma unroll
    for (int f = 0; f < 2; ++f)
#pragma unroll
      for (int g = 0; g < 2; ++g)
#pragma unroll
        for (int kk = 0; kk < 2; ++kk)
          acc[2 + f][g] = __builtin_amdgcn_mfma_f32_16x16x32_bf16(af_hi[f][kk], bfr0[g][kk],
                                                                  acc[2 + f][g], 0, 0, 0);
    __builtin_amdgcn_s_setprio(0);
    asm volatile("s_waitcnt vmcnt(0)" ::: "memory");
    __builtin_amdgcn_s_barrier();

    // ---- P2 ----
    RD_A(af_lo, 1, 0);
    RD_B(bfr0, 1, 0);
    RD_B(bfr1, 1, 1);
    if (nl) {
      STAGE_A(0, k0e + 128, 0);
      STAGE_A(1, k0e + 128, 0);
      STAGE_A(2, k0e + 128, 0);
      STAGE_A(3, k0e + 128, 0);
      STAGE_B(0, k0e + 128, 0);
      STAGE_B(1, k0e + 128, 0);
    }
    __builtin_amdgcn_s_barrier();
    asm volatile("s_waitcnt lgkmcnt(0)" ::: "memory");
    __builtin_amdgcn_sched_barrier(0);
    __builtin_amdgcn_s_setprio(1);
    MFMA_QPAIR(af_lo, bfr0, bfr1, 0);
    __builtin_amdgcn_s_setprio(0);
    __builtin_amdgcn_s_barrier();

    // ---- P3 ----
    RD_A(af_hi, 1, 1);
    __builtin_amdgcn_s_barrier();
    asm volatile("s_waitcnt lgkmcnt(0)" ::: "memory");
    __builtin_amdgcn_sched_barrier(0);
    __builtin_amdgcn_s_setprio(1);
#pragma unroll
    for (int f = 0; f < 2; ++f)
#pragma unroll
      for (int g = 0; g < 2; ++g)
#pragma unroll
        for (int kk = 0; kk < 2; ++kk)
          acc[2 + f][2 + g] = __builtin_amdgcn_mfma_f32_16x16x32_bf16(
              af_hi[f][kk], bfr1[g][kk], acc[2 + f][2 + g], 0, 0, 0);
#pragma unroll
    for (int f = 0; f < 2; ++f)
#pragma unroll
      for (int g = 0; g < 2; ++g)
#pragma unroll
        for (int kk = 0; kk < 2; ++kk)
          acc[2 + f][g] = __builtin_amdgcn_mfma_f32_16x16x32_bf16(af_hi[f][kk], bfr0[g][kk],
                                                                  acc[2 + f][g], 0, 0, 0);
    __builtin_amdgcn_s_setprio(0);
    if (nl) asm volatile("s_waitcnt vmcnt(0)" ::: "memory");
    __builtin_amdgcn_s_barrier();
  }
#undef STAGE_A
#undef STAGE_B
#undef RD_A
#undef RD_B
#undef MFMA_QPAIR

#pragma unroll
  for (int i = 0; i < 4; ++i) {
    const int rbase = m0 + wr * 64 + i * 16 + (quad << 2);
#pragma unroll
    for (int j = 0; j < 4; ++j) {
      const int col = n0 + wc * 64 + j * 16 + frow;
#pragma unroll
      for (int rg = 0; rg < 4; ++rg)
        Cp[(size_t)ks * pstride + (size_t)(rbase + rg) * N + col] = f2bf_bits(acc[i][j][rg]);
    }
  }
}

// ---------------- 256x128 MFMA GEMM, TRIPLE-buffered counted pipeline (v9 primary) -----------
// R8 synthesis: v2 (fine phases + counted vmcnt, 8 MFMA/barrier-pair) was sync-bound;
// v4 (16 MFMA/pair but vmcnt(0) full-drain each tile) was seal-stall-bound. m201's 62%
// has BOTH big MFMA clusters AND a counted seal. v9 = v4 geometry/numerics + triple
// buffer (3 x [A 32KB + B 16KB] = 144KB LDS) so the seal becomes vmcnt(6):
//   stage tile t+2 during tile t (6 issues: 3 in PhA, 3 in PhB);
//   at end of tile t, FIFO = [t+1:6][t+2:6] -> vmcnt(6) drains t+1's issues, which were
//   issued during tile t-1 (~4 phases, ~1600cyc slack >> 900cyc HBM) -> near-zero stall;
//   never drains to 0 until the tail (t=nT-2: vmcnt(0) seals the last tile).
// Triple-buffering also removes v4's WAR barriers: stages target buf[(t+2)%3], last read
// during tile t-1, and every wave's lgkm0 for those reads preceded the single barrier at
// end of tile t-1 -> ONE barrier per tile (vs v4's 4). Per-phase lgkm0+sched_barrier
// orders own ds_reads before own MFMA (rule #18).
// MFMA order per acc element byte-identical to v4/R7 (q0,q1,q2,q3; kk ascending; KS=4;
// bf16 rounding at C-write) -> absmax unchanged (0.0234375 with the R7 LN kernels).
__global__ __launch_bounds__(512, 2) void gemm_tri(const u16* __restrict__ A,
                                                   const u16* __restrict__ B,
                                                   u16* __restrict__ Cp, size_t pstride, int N,
                                                   int Ktot) {
  extern __shared__ u16 smem[];
  u16* sA = smem;          // [3][256*64]  96 KiB
  u16* sB = smem + 49152;  // [3][128*64]  48 KiB
  const int tid = threadIdx.x;
  const int wave = tid >> 6;
  const int lane = tid & 63;
  const int wr = wave >> 1;  // 0..3 -> 64-row group
  const int wc = wave & 1;   // 0..1 -> 64-col group
  const int m0 = blockIdx.x * 256;
  const int n0 = blockIdx.y * 128;
  const int ks = blockIdx.z;
  const int Kper = Ktot / gridDim.z;
  const int kb = ks * Kper;
  const int nT = Kper >> 6;  // BK=64 tiles (32 at KS=4)
  const int r_l = tid >> 3;  // row within 64-row load group
  const int g8 = (tid & 7) << 3;
  const int frow = lane & 15;
  const int quad = lane >> 4;
  const int sw = frow & 7;
  const int o0 = (quad ^ sw) << 3;        // swizzled elem offset, kk=0
  const int o1 = ((4 | quad) ^ sw) << 3;  // swizzled elem offset, kk=1

  const u16* Abase = A + (size_t)(m0 + r_l) * Ktot + g8;
  const u16* Bbase = B + (size_t)(n0 + r_l) * Ktot + g8;

#define STAGE_A(l, k0, b) \
  gl_lds16(Abase + (size_t)(l) * 64 * Ktot + (k0), sA + (b)*16384 + (l)*4096 + wave * 512)
#define STAGE_B(l, k0, b) \
  gl_lds16(Bbase + (size_t)(l) * 64 * Ktot + (k0), sB + (b)*8192 + (l)*4096 + wave * 512)
#define RD_A(dst, b, qm_)                                               \
  do {                                                                  \
    const u16* _p = sA + (b)*16384 + (wr * 64 + (qm_)*32 + frow) * 64;  \
    dst[0][0] = *(const short8*)(_p + o0);                              \
    dst[0][1] = *(const short8*)(_p + o1);                              \
    dst[1][0] = *(const short8*)(_p + 1024 + o0);                       \
    dst[1][1] = *(const short8*)(_p + 1024 + o1);                       \
  } while (0)
#define RD_B(dst, b, half_)                                              \
  do {                                                                   \
    const u16* _p = sB + (b)*8192 + (wc * 64 + (half_)*32 + frow) * 64;  \
    dst[0][0] = *(const short8*)(_p + o0);                               \
    dst[0][1] = *(const short8*)(_p + o1);                               \
    dst[1][0] = *(const short8*)(_p + 1024 + o0);                        \
    dst[1][1] = *(const short8*)(_p + 1024 + o1);                        \
  } while (0)
#define MFMA_QPAIR(ar, b0_, b1_, qm_)                                               \
  do {                                                                              \
    _Pragma("unroll") for (int f = 0; f < 2; ++f) _Pragma("unroll") for (int g = 0; \
                                                                         g < 2;    \
                                                                         ++g)      \
        _Pragma("unroll") for (int kk = 0; kk < 2; ++kk) acc[(qm_)*2 + f][g] =      \
            __builtin_amdgcn_mfma_f32_16x16x32_bf16(ar[f][kk], b0_[g][kk],          \
                                                    acc[(qm_)*2 + f][g], 0, 0, 0); \
    _Pragma("unroll") for (int f = 0; f < 2; ++f) _Pragma("unroll") for (int g = 0; \
                                                                         g < 2;    \
                                                                         ++g)      \
        _Pragma("unroll") for (int kk = 0; kk < 2; ++kk) acc[(qm_)*2 + f][2 + g] =  \
            __builtin_amdgcn_mfma_f32_16x16x32_bf16(ar[f][kk], b1_[g][kk],          \
                                                    acc[(qm_)*2 + f][2 + g], 0, 0,  \
                                                    0);                             \
  } while (0)

  f32x4 acc[4][4];
#pragma unroll
  for (int i = 0; i < 4; ++i)
#pragma unroll
    for (int j = 0; j < 4; ++j) acc[i][j] = (f32x4){0.f, 0.f, 0.f, 0.f};

  short8 af_lo[2][2];
  short8 af_hi[2][2];
  short8 bfr0[2][2];
  short8 bfr1[2][2];

  // Prologue: stage tile0 -> buf0 (6 issues), tile1 -> buf1 (6 issues); seal tile0.
  STAGE_A(0, kb, 0);
  STAGE_A(1, kb, 0);
  STAGE_A(2, kb, 0);
  STAGE_A(3, kb, 0);
  STAGE_B(0, kb, 0);
  STAGE_B(1, kb, 0);
  STAGE_A(0, kb + 64, 1);
  STAGE_A(1, kb + 64, 1);
  STAGE_A(2, kb + 64, 1);
  STAGE_A(3, kb + 64, 1);
  STAGE_B(0, kb + 64, 1);
  STAGE_B(1, kb + 64, 1);
  asm volatile("s_waitcnt vmcnt(6)" ::: "memory");  // drain tile0's 6; tile1 in flight
  __builtin_amdgcn_s_barrier();

  int bc = 0;  // buffer holding the current tile
  for (int t = 0; t < nT; ++t) {
    const int k0 = kb + (t << 6);
    int bs = bc + 2;
    if (bs >= 3) bs -= 3;            // stage target = buf[(t+2)%3]
    const bool st = (t + 2 < nT);    // stages exist this tile
    // ---- PhA: quadrants q0,q1 (rows 0..31 of wave's 64) ----
    RD_A(af_lo, bc, 0);
    RD_B(bfr0, bc, 0);
    RD_B(bfr1, bc, 1);
    if (st) {
      STAGE_A(0, k0 + 128, bs);
      STAGE_A(1, k0 + 128, bs);
      STAGE_A(2, k0 + 128, bs);
    }
    asm volatile("s_waitcnt lgkmcnt(0)" ::: "memory");
    __builtin_amdgcn_sched_barrier(0);
    __builtin_amdgcn_s_setprio(1);
    MFMA_QPAIR(af_lo, bfr0, bfr1, 0);
    __builtin_amdgcn_s_setprio(0);
    // ---- PhB: quadrants q2,q3 (rows 32..63) ----
    RD_A(af_hi, bc, 1);
    if (st) {
      STAGE_A(3, k0 + 128, bs);
      STAGE_B(0, k0 + 128, bs);
      STAGE_B(1, k0 + 128, bs);
    }
    asm volatile("s_waitcnt lgkmcnt(0)" ::: "memory");
    __builtin_amdgcn_sched_barrier(0);
    __builtin_amdgcn_s_setprio(1);
#pragma unroll
    for (int f = 0; f < 2; ++f)
#pragma unroll
      for (int g = 0; g < 2; ++g)
#pragma unroll
        for (int kk = 0; kk < 2; ++kk)
          acc[2 + f][2 + g] = __builtin_amdgcn_mfma_f32_16x16x32_bf16(
              af_hi[f][kk], bfr1[g][kk], acc[2 + f][2 + g], 0, 0, 0);
#pragma unroll
    for (int f = 0; f < 2; ++f)
#pragma unroll
      for (int g = 0; g < 2; ++g)
#pragma unroll
        for (int kk = 0; kk < 2; ++kk)
          acc[2 + f][g] = __builtin_amdgcn_mfma_f32_16x16x32_bf16(af_hi[f][kk], bfr0[g][kk],
                                                                  acc[2 + f][g], 0, 0, 0);
    __builtin_amdgcn_s_setprio(0);
    // ---- single counted seal + single barrier per tile ----
    if (st)
      asm volatile("s_waitcnt vmcnt(6)" ::: "memory");  // seal tile t+1 (issued at t-1)
    else if (t + 1 < nT)
      asm volatile("s_waitcnt vmcnt(0)" ::: "memory");  // tail: seal final tile
    __builtin_amdgcn_s_barrier();
    bc += 1;
    if (bc >= 3) bc -= 3;
  }
#undef STAGE_A
#undef STAGE_B
#undef RD_A
#undef RD_B
#undef MFMA_QPAIR

#pragma unroll
  for (int i = 0; i < 4; ++i) {
    const int rbase = m0 + wr * 64 + i * 16 + (quad << 2);
#pragma unroll
    for (int j = 0; j < 4; ++j) {
      const int col = n0 + wc * 64 + j * 16 + frow;
#pragma unroll
      for (int rg = 0; rg < 4; ++rg)
        Cp[(size_t)ks * pstride + (size_t)(rbase + rg) * N + col] = f2bf_bits(acc[i][j][rg]);
    }
  }
}

// ---------------- p/q prep: pT=|tr| transposed, q=|ct|/(1e-8+Sp*Sq) ----------------
__global__ void prep_pq(const float* __restrict__ trct, float* __restrict__ pT,
                        float* __restrict__ q) {
  int t = blockIdx.x;
  int lane = threadIdx.x;  // 64
  float tr = trct[t * 128 + lane];
  float ct = trct[t * 128 + 64 + lane];
  float ap = fabsf(tr), aq = fabsf(ct);
  float Sp = wave_sum(ap);
  float Sq = wave_sum(aq);
  float denom = 1e-8f + Sp * Sq;
  pT[lane * T_LEN + t] = ap;  // transposed for shuffle-broadcast in scans
  q[t * 64 + lane] = aq / denom;
}

// ---------------- scan phase 1: per-chunk affine summary (A,B) ----------------
__global__ void scan_phase1(const float* __restrict__ pT, const float* __restrict__ q,
                            const unsigned char* __restrict__ st8, const int* __restrict__ st32,
                            const int* __restrict__ modep, const float* __restrict__ a,
                            const float* __restrict__ b, float4* __restrict__ chunkbuf) {
  int chunk = blockIdx.x, r = blockIdx.y, c = threadIdx.x;
  int mode = modep[0];
  int t0 = chunk * CLEN;
  float na = -fabsf(a[r]);
  float rho = __expf(na);
  float bb = b[c];
  float er = rho * __cosf(bb), ei = rho * __sinf(bb);
  float pv = pT[r * T_LEN + t0 + c];             // lane c holds p for step c
  int sv = read_start(st8, st32, mode, t0 + c);  // lane c holds start for step c
  unsigned long long bal = __ballot(sv != 0);
  float Ar, Ai;
  if (bal) {
    Ar = 0.f; Ai = 0.f;
  } else {
    float mag = __expf(64.f * na);
    float ang = 64.f * bb;
    Ar = mag * __cosf(ang);
    Ai = mag * __sinf(ang);
  }
  int L = bal ? (63 - __builtin_clzll(bal)) : 0;  // wave-uniform
  float Br = 0.f, Bi = 0.f;
  const float* qrow = q + (size_t)t0 * 64 + c;
  for (int i = L; i < CLEN; ++i) {
    float pre = __shfl(pv, i) * qrow[i * 64];
    float nBr = er * Br - ei * Bi + pre;
    Bi = er * Bi + ei * Br;
    Br = nBr;
  }
  chunkbuf[((size_t)chunk * 64 + r) * 64 + c] = make_float4(Ar, Ai, Br, Bi);
}

// ---------------- scan phase 2: sequential chunk combine ----------------
__global__ void scan_phase2(const float4* __restrict__ chunkbuf, const float* __restrict__ state,
                            float2* __restrict__ s0buf) {
  int r = blockIdx.x, c = threadIdx.x;
  float Sr = state[r * 64 + c], Si = 0.f;
  for (int k = 0; k < NCHUNK; ++k) {
    s0buf[((size_t)k * 64 + r) * 64 + c] = make_float2(Sr, Si);
    float4 ab = chunkbuf[((size_t)k * 64 + r) * 64 + c];
    float nSr = ab.x * Sr - ab.y * Si + ab.z;
    Si = ab.x * Si + ab.y * Sr + ab.w;
    Sr = nSr;
  }
}

// ---------------- scan phase 3: replay + packed log-polar features (swizzled store) ----
__global__ void scan_phase3(const float* __restrict__ pT, const float* __restrict__ q,
                            const unsigned char* __restrict__ st8, const int* __restrict__ st32,
                            const int* __restrict__ modep, const float* __restrict__ a,
                            const float* __restrict__ b, const float2* __restrict__ s0buf,
                            u32* __restrict__ scaled, int c0) {
  int chunk = c0 + blockIdx.x, r = blockIdx.y, c = threadIdx.x;
  int mode = modep[0];
  int t0 = chunk * CLEN;
  float rho = __expf(-fabsf(a[r]));
  float bb = b[c];
  float er = rho * __cosf(bb), ei = rho * __sinf(bb);
  float pv = pT[r * T_LEN + t0 + c];
  int sv = read_start(st8, st32, mode, t0 + c);
  float2 s0 = s0buf[((size_t)chunk * 64 + r) * 64 + c];
  float Sr = s0.x, Si = s0.y;
  int tl0 = (chunk - c0) * CLEN;
  const float* qrow = q + (size_t)t0 * 64 + c;
  u32* srow = scaled + (size_t)tl0 * 4096;
  const int Ldw = r * 64 + c;
#pragma unroll 4
  for (int i = 0; i < CLEN; ++i) {
    float qt = qrow[i * 64];
    float pt = __shfl(pv, i);
    int st = __shfl(sv, i);
    float pre = pt * qt;
    float cer = st ? 0.f : er;
    float cei = st ? 0.f : ei;
    float nSr = cer * Sr - cei * Si + pre;
    Si = cer * Si + cei * Sr;
    Sr = nSr;
    float m2 = fmaf(Sr, Sr, Si * Si);
    float rsq = rsqrtf(fmaxf(m2, 1e-30f));
    float m = m2 * rsq;
    float sc = __log2f(1.0f + m) * 0.6931471805599453f * rsq;
    u32 pack = ((u32)f2bf_bits(sc * Sr) << 16) | (u32)f2bf_bits(sc * Si);
    srow[(size_t)i * 4096 + (Ldw ^ ((i & 7) << 2))] = pack;
  }
}

// ---------------- LN + LeakyReLU over bf16 split-K partials -> z0bf (vectorized, 1 wave/row) ----
__global__ void ln_act16(const u16* __restrict__ parts, int KS, size_t pstride,
                         const float* __restrict__ bias, const float* __restrict__ gam,
                         const float* __restrict__ bet, u16* __restrict__ zbf) {
  int t = blockIdx.x, lane = threadIdx.x;  // 64 lanes
  int e0 = lane << 3;
  size_t o = (size_t)t * D_DIM + e0;
  float4 ba = *(const float4*)(bias + e0);
  float4 bb4 = *(const float4*)(bias + e0 + 4);
  float v[8] = {ba.x, ba.y, ba.z, ba.w, bb4.x, bb4.y, bb4.z, bb4.w};
  for (int ks = 0; ks < KS; ++ks) {
    short8 p = *(const short8*)(parts + (size_t)ks * pstride + o);
#pragma unroll
    for (int j = 0; j < 8; ++j) v[j] += bf2f((u16)p[j]);
  }
  float s8 = 0.f;
#pragma unroll
  for (int j = 0; j < 8; ++j) s8 += v[j];
  float mean = wave_sum(s8) * (1.f / 512.f);
  float d[8];
  float sq = 0.f;
#pragma unroll
  for (int j = 0; j < 8; ++j) {
    d[j] = v[j] - mean;
    sq = fmaf(d[j], d[j], sq);
  }
  float var = wave_sum(sq) * (1.f / 512.f);
  float rstd = rsqrtf(var + 1e-5f);
  float4 g0v = *(const float4*)(gam + e0);
  float4 g1v = *(const float4*)(gam + e0 + 4);
  float4 t0v = *(const float4*)(bet + e0);
  float4 t1v = *(const float4*)(bet + e0 + 4);
  float gg[8] = {g0v.x, g0v.y, g0v.z, g0v.w, g1v.x, g1v.y, g1v.z, g1v.w};
  float tt[8] = {t0v.x, t0v.y, t0v.z, t0v.w, t1v.x, t1v.y, t1v.z, t1v.w};
  short8 r;
#pragma unroll
  for (int j = 0; j < 8; ++j) {
    float z = d[j] * rstd * gg[j] + tt[j];
    z = z > 0.f ? z : 0.01f * z;
    r[j] = (short)f2bf_bits(z);
  }
  *(short8*)(zbf + o) = r;
}

// ---------------- LN + LeakyReLU over fp32 y (W1 epilogue; vectorized, 1 wave/row) ----------
__global__ void ln_act32(const float* __restrict__ y, const float* __restrict__ bias,
                         const float* __restrict__ gam, const float* __restrict__ bet,
                         const float* __restrict__ xsrc, float* __restrict__ xdst,
                         u16* __restrict__ xbf_next, float* __restrict__ finout) {
  int t = blockIdx.x, lane = threadIdx.x;  // 64 lanes
  int e0 = lane << 3;
  size_t o = (size_t)t * D_DIM + e0;
  float4 y0 = *(const float4*)(y + o);
  float4 y1 = *(const float4*)(y + o + 4);
  float4 ba = *(const float4*)(bias + e0);
  float4 bb4 = *(const float4*)(bias + e0 + 4);
  float v[8] = {y0.x + ba.x, y0.y + ba.y, y0.z + ba.z, y0.w + ba.w,
                y1.x + bb4.x, y1.y + bb4.y, y1.z + bb4.z, y1.w + bb4.w};
  float s8 = 0.f;
#pragma unroll
  for (int j = 0; j < 8; ++j) s8 += v[j];
  float mean = wave_sum(s8) * (1.f / 512.f);
  float d[8];
  float sq = 0.f;
#pragma unroll
  for (int j = 0; j < 8; ++j) {
    d[j] = v[j] - mean;
    sq = fmaf(d[j], d[j], sq);
  }
  float var = wave_sum(sq) * (1.f / 512.f);
  float rstd = rsqrtf(var + 1e-5f);
  float4 g0v = *(const float4*)(gam + e0);
  float4 g1v = *(const float4*)(gam + e0 + 4);
  float4 t0v = *(const float4*)(bet + e0);
  float4 t1v = *(const float4*)(bet + e0 + 4);
  float gg[8] = {g0v.x, g0v.y, g0v.z, g0v.w, g1v.x, g1v.y, g1v.z, g1v.w};
  float tt[8] = {t0v.x, t0v.y, t0v.z, t0v.w, t1v.x, t1v.y, t1v.z, t1v.w};
  float z[8];
#pragma unroll
  for (int j = 0; j < 8; ++j) {
    float zz = d[j] * rstd * gg[j] + tt[j];
    z[j] = zz > 0.f ? zz : 0.01f * zz;
  }
  if (xdst) {
    float4 x0 = *(const float4*)(xsrc + o);
    float4 x1 = *(const float4*)(xsrc + o + 4);
    float xx[8] = {x0.x + z[0], x0.y + z[1], x0.z + z[2], x0.w + z[3],
                   x1.x + z[4], x1.y + z[5], x1.z + z[6], x1.w + z[7]};
    *(float4*)(xdst + o) = make_float4(xx[0], xx[1], xx[2], xx[3]);
    *(float4*)(xdst + o + 4) = make_float4(xx[4], xx[5], xx[6], xx[7]);
    short8 r;
#pragma unroll
    for (int j = 0; j < 8; ++j) r[j] = (short)f2bf_bits(xx[j]);
    *(short8*)(xbf_next + o) = r;
  }
  if (finout) {
    *(float4*)(finout + o) = make_float4(z[0], z[1], z[2], z[3]);
    *(float4*)(finout + o + 4) = make_float4(z[4], z[5], z[6], z[7]);
  }
}

__global__ void err_signal(float* __restrict__ out, float code) {
  if (threadIdx.x == 0) out[0] = code;
}

// ---------------- host launch ----------------
extern "C" void kernel_launch(void* const* d_in, const int* in_sizes, int n_in, void* d_out,
                              int out_size, void* d_ws, size_t ws_size, hipStream_t stream) {
  const float* x_in = (const float*)d_in[0];
  const float* state = (const float*)d_in[1];
  const unsigned char* start8 = (const unsigned char*)d_in[2];
  const int* start32 = (const int*)d_in[2];
  const float* Wtr = (const float*)d_in[3];
  const float* Wc = (const float*)d_in[4];
  const float* a_in = (const float*)d_in[5];
  const float* b_in = (const float*)d_in[6];
  const float* W0 = (const float*)d_in[7];
  const float* b0 = (const float*)d_in[8];
  const float* g0 = (const float*)d_in[9];
  const float* beta0 = (const float*)d_in[10];
  const float* W1 = (const float*)d_in[11];
  const float* b1 = (const float*)d_in[12];
  const float* g1 = (const float*)d_in[13];
  const float* beta1 = (const float*)d_in[14];
  float* out = (float*)d_out;

  // one-time: allow 96 KiB / 144 KiB dynamic LDS for the GEMMs
  static int attr_state = 0;  // 0 unset, 1 ok, -1 failed
  if (attr_state == 0)
    attr_state = (hipFuncSetAttribute((const void*)gemm_8ph,
                                      hipFuncAttributeMaxDynamicSharedMemorySize,
                                      98304) == hipSuccess)
                     ? 1
                     : -1;
  static int attr_tri_state = 0;
  if (attr_tri_state == 0)
    attr_tri_state = (hipFuncSetAttribute((const void*)gemm_tri,
                                          hipFuncAttributeMaxDynamicSharedMemorySize,
                                          147456) == hipSuccess)
                         ? 1
                         : -1;
  const bool attr_ok = (attr_state == 1);
  const bool attr_tri_ok = (attr_tri_state == 1);

  char* w = (char*)d_ws;
  auto alloc = [&](size_t bytes) {
    char* ptr = w;
    w += (bytes + 255) & ~(size_t)255;
    return ptr;
  };
  float* x_ws = (float*)alloc(4ull * T_LEN * D_DIM);            // 8 MB
  u16* xbf = (u16*)alloc(2ull * T_LEN * D_DIM);                 // 4 MB
  u16* wcat = (u16*)alloc(2ull * 128 * D_DIM);                  // 128 KB
  u16* w0bf = (u16*)alloc(2ull * D_DIM * F_DIM);                // 8 MB (per-layer)
  u16* w1bf = (u16*)alloc(2ull * 3 * D_DIM * D_DIM);            // 1.5 MB (all layers)
  float* trct = (float*)alloc(4ull * T_LEN * 128);              // 2 MB
  float* pTbuf = (float*)alloc(4ull * T_LEN * 64);              // 1 MB
  float* qbuf = (float*)alloc(4ull * T_LEN * 64);               // 1 MB
  float4* chunkbuf = (float4*)alloc(16ull * NCHUNK * 64 * 64);  // 4 MB
  float2* s0buf = (float2*)alloc(8ull * NCHUNK * 64 * 64);      // 2 MB
  u16* z0bf = (u16*)alloc(2ull * T_LEN * D_DIM);                // 4 MB
  float* ybuf = (float*)alloc(4ull * T_LEN * D_DIM);            // 8 MB (W1 out)
  int* modep = (int*)alloc(256);
  size_t base1 = (size_t)(w - (char*)d_ws);

  if (n_in != 15) {
    err_signal<<<1, 64, 0, stream>>>(out, 9e6f + 1000.f * n_in);
    return;
  }
  const size_t MB = 1ull << 20;
  const size_t pstride = (size_t)T_LEN * D_DIM;  // elements per partial slab
  int KS, nseg;
  if (ws_size >= base1 + 16 * MB + 64 * MB) { KS = 4; nseg = 1; }
  else if (ws_size >= base1 + 16 * MB + 32 * MB) { KS = 4; nseg = 2; }
  else if (ws_size >= base1 + 8 * MB + 32 * MB) { KS = 2; nseg = 2; }
  else if (ws_size >= base1 + 8 * MB + 16 * MB) { KS = 2; nseg = 4; }
  else if (ws_size >= base1 + 4 * MB + 16 * MB) { KS = 1; nseg = 4; }
  else {
    err_signal<<<1, 64, 0, stream>>>(out, 9e6f);
    return;
  }
  const int seg_rows = T_LEN / nseg;
  const int seg_chunks = NCHUNK / nseg;
  u16* ypart = (u16*)alloc(2ull * KS * pstride);
  u16* scaled = (u16*)alloc(2ull * seg_rows * F_DIM);

  const bool use_tri = (nseg == 1) && attr_tri_ok;
  const bool use8 = (nseg == 1) && attr_ok && !use_tri;

  detect_start<<<1, 256, 0, stream>>>(start8, modep);
  f2bf<<<(T_LEN * D_DIM) / 256, 256, 0, stream>>>(x_in, xbf, T_LEN * D_DIM);
  f2bf<<<(3 * D_DIM * D_DIM) / 256, 256, 0, stream>>>(W1, w1bf, 3 * D_DIM * D_DIM);

  for (int l = 0; l < 3; ++l) {
    const float* Wtr_l = Wtr + (size_t)l * 64 * D_DIM;
    const float* Wc_l = Wc + (size_t)l * 64 * D_DIM;
    const float* a_l = a_in + l * 64;
    const float* b_l = b_in + l * 64;
    const float* W0_l = W0 + (size_t)l * D_DIM * F_DIM;
    const u16* w1bf_l = w1bf + (size_t)l * D_DIM * D_DIM;
    const float* state_l = state + (size_t)l * 64 * 64;
    const float* xsrc = (l == 0) ? x_in : x_ws;

    k_conv<<<(128 * D_DIM + D_DIM * F_DIM) / 256, 256, 0, stream>>>(Wtr_l, Wc_l, wcat, W0_l,
                                                                    w0bf);
    // trct (4096 x 128) = xbf @ wcat^T
    gemm_bt<64, 64, 2, 2><<<dim3(T_LEN / 64, 2), 256, 0, stream>>>(xbf, wcat, trct, T_LEN, 128,
                                                                   D_DIM);
    prep_pq<<<T_LEN, 64, 0, stream>>>(trct, pTbuf, qbuf);
    scan_phase1<<<dim3(NCHUNK, 64), 64, 0, stream>>>(pTbuf, qbuf, start8, start32, modep, a_l,
                                                     b_l, chunkbuf);
    scan_phase2<<<64, 64, 0, stream>>>(chunkbuf, state_l, s0buf);

    for (int h = 0; h < nseg; ++h) {
      scan_phase3<<<dim3(seg_chunks, 64), 64, 0, stream>>>(pTbuf, qbuf, start8, start32, modep,
                                                           a_l, b_l, s0buf, (u32*)scaled,
                                                           h * seg_chunks);
      if (use_tri)
        gemm_tri<<<dim3(seg_rows / 256, D_DIM / 128, KS), 512, 147456, stream>>>(
            scaled, w0bf, ypart + (size_t)h * seg_rows * D_DIM, pstride, D_DIM, F_DIM);
      else if (use8)
        gemm_8ph<<<dim3(seg_rows / 256, D_DIM / 128, KS), 512, 98304, stream>>>(
            scaled, w0bf, ypart + (size_t)h * seg_rows * D_DIM, pstride, D_DIM, F_DIM);
      else
        gemm128<<<dim3(seg_rows / 128, D_DIM / 128, KS), 256, 0, stream>>>(
            scaled, w0bf, ypart + (size_t)h * seg_rows * D_DIM, pstride, D_DIM, F_DIM);
    }
    ln_act16<<<T_LEN, 64, 0, stream>>>(ypart, KS, pstride, b0 + l * D_DIM, g0 + l * D_DIM,
                                       beta0 + l * D_DIM, z0bf);
    // y2 = z0 (4096x512) @ W1 (512x512)^T — no split-K, grid 64x8 = 512 blocks
    gemm_bt<64, 64, 2, 2><<<dim3(T_LEN / 64, D_DIM / 64), 256, 0, stream>>>(z0bf, w1bf_l, ybuf,
                                                                            T_LEN, D_DIM, D_DIM);
    ln_act32<<<T_LEN, 64, 0, stream>>>(ybuf, b1 + l * D_DIM, g1 + l * D_DIM, beta1 + l * D_DIM,
                                       (l < 2) ? xsrc : nullptr, (l < 2) ? x_ws : nullptr,
                                       (l < 2) ? xbf : nullptr, (l == 2) ? out : nullptr);
  }
}